// Round 3
// baseline (294.726 us; speedup 1.0000x reference)
//
#include <hip/hip_runtime.h>
#include <cstdint>

typedef unsigned short u16;
typedef unsigned int   u32;
typedef __attribute__((ext_vector_type(8))) short  short8;
typedef __attribute__((ext_vector_type(4))) float  floatx4;
typedef __attribute__((ext_vector_type(4))) unsigned int u32x4;

#define NPTS 524288   // B*N2*K
#define NREP 4        // stat-accumulator replicas (atomic contention / NREP)

__device__ __forceinline__ float b2f(u16 h) { return __uint_as_float(((u32)h) << 16); }
__device__ __forceinline__ u16 f2b(float f) {
  u32 u = __float_as_uint(f);
  return (u16)((u + 0x7FFFu + ((u >> 16) & 1u)) >> 16);
}
__device__ __forceinline__ u32 pk_bf16(float lo, float hi) {
  return (u32)f2b(lo) | ((u32)f2b(hi) << 16);
}
__device__ __forceinline__ short8 ld_frag8(const u16* p) {
  union { uint4 q; short8 s; } x;
  x.q = *(const uint4*)p;
  return x.s;
}
__device__ __forceinline__ short8 u4_to_s8(uint4 q) {
  union { uint4 q; short8 s; } x; x.q = q; return x.s;
}
__device__ __forceinline__ u32x4 nt_ld4(const void* p) {
  return __builtin_nontemporal_load((const u32x4*)p);
}

// ---- combined prep: featT transpose + xyzB pack + W->bf16 padded + stat zero ----
// Wb layout (u16): W0 64 x pitch104 @0 (cols 67..103 zero) ; W1 64 x pitch72 @6656 ; W2 128 x pitch72 @11264
__global__ __launch_bounds__(256) void prep_all(const float* __restrict__ inf,
                                                const float* __restrict__ ixyz,
                                                const float* __restrict__ W0,
                                                const float* __restrict__ W1,
                                                const float* __restrict__ W2,
                                                u16* __restrict__ featT,
                                                u16* __restrict__ xyzB,
                                                u16* __restrict__ Wb,
                                                float* __restrict__ gz) {
  __shared__ float tile[32 * 33];
  const int bk = blockIdx.x, t = threadIdx.x;
  if (bk < 4096) {          // in_feature [b][c][n] f32 -> featT [b][n][c] bf16
    int b = bk >> 8, rem = bk & 255, cc = rem >> 7, nc = rem & 127;
    #pragma unroll
    for (int i = 0; i < 4; ++i) {
      int flat = t + i * 256;
      int cl = flat >> 5, nl = flat & 31;
      tile[cl * 33 + nl] = inf[(size_t)((b * 64) + cc * 32 + cl) * 4096 + nc * 32 + nl];
    }
    __syncthreads();
    #pragma unroll
    for (int i = 0; i < 4; ++i) {
      int flat = t + i * 256;
      int nl = flat >> 5, cl = flat & 31;
      featT[(size_t)((b << 12) + nc * 32 + nl) * 64 + cc * 32 + cl] = f2b(tile[cl * 33 + nl]);
    }
  } else if (bk < 4352) {   // in_xyz [b][3][n] -> xyzB [b][n][4xbf16] (8 B records)
    int g = (bk - 4096) * 256 + t;
    int b = g >> 12, n = g & 4095;
    const float* p = ixyz + (size_t)b * 12288;
    u32 lo = pk_bf16(p[n], p[4096 + n]);
    u32 hi = (u32)f2b(p[8192 + n]);
    *(uint2*)(xyzB + (size_t)g * 4) = make_uint2(lo, hi);
  } else if (bk < 4432) {   // weights: 20480 u16 over 80 blocks
    int s = (bk - 4352) * 256 + t;
    u16 v = 0;
    if (s < 6656)       { int o = s / 104, c = s % 104; if (c < 67) v = f2b(W0[o * 67 + c]); }
    else if (s < 11264) { int q = s - 6656;  int o = q / 72, c = q % 72; if (c < 64) v = f2b(W1[o * 64 + c]); }
    else                { int q = s - 11264; int o = q / 72, c = q % 72; if (c < 64) v = f2b(W2[o * 64 + c]); }
    Wb[s] = v;
  } else {                  // zero 2048 floats of stat accumulators (gs0|gs1|gs2)
    #pragma unroll
    for (int i = 0; i < 8; ++i) gz[t + i * 256] = 0.f;
  }
}

// ---- fused layer: direct global->reg A-fragments, NT hints on streams ----
// GATHER layer: xyz[id]-oxyz recentering folded out of the gather:
//   concat(feat, xyz-oxyz)@W == concat(feat, xyz)@W - (oxyz @ W[:,64:67])
// The per-(och,n2) correction is computed in the preamble into LDS and
// subtracted from the accumulator (8 distinct n2 per block).
// Stats: per-block LDS reduce -> one unsafeAtomicAdd per channel into NREP-replicated f32 buf.
template<int KSTEPS, int OCH, bool GATHER, bool MAXOUT>
__global__ __launch_bounds__(256, MAXOUT ? 4 : 5) void gemm_layer(
    const u16* __restrict__ xsrc, const u16* __restrict__ xyzB,
    const float* __restrict__ oxyz, const int* __restrict__ nbr,
    const u16* __restrict__ Wb,
    const float* __restrict__ gsin, const float* __restrict__ gam,
    const float* __restrict__ bet,
    u16* __restrict__ yout, u32* __restrict__ gm,
    float* __restrict__ gsout) {
  constexpr int PITCH = KSTEPS * 32 + 8;   // 104 / 72
  __shared__ __align__(16) u16 wsh[OCH * PITCH];
  __shared__ float red[512];
  __shared__ float ss[GATHER ? 4 : 128];
  __shared__ float corr[GATHER ? 8 : 1][64];

  const int t = threadIdx.x, blk = blockIdx.x;
  const int lane = t & 63, wv = t >> 6, lr = lane & 15, quad = lane >> 4;
  const int P0 = blk * 256;
  const int b = blk >> 7;

  { // W -> LDS (bf16, padded pitch)
    const u32* src = (const u32*)Wb;
    u32* dst = (u32*)wsh;
    constexpr int NW = OCH * PITCH / 2;
    #pragma unroll
    for (int i = 0; i < NW / 256; ++i) dst[t + i * 256] = src[t + i * 256];
  }
  if constexpr (GATHER) {   // oxyz @ W[:,64:67] correction table: 8 n2 x 64 och
    #pragma unroll
    for (int half = 0; half < 2; ++half) {
      int e = t + half * 256, nn = e >> 6, och = e & 63;
      int n2 = (blk * 8 + nn) & 1023;
      float c = 0.f;
      #pragma unroll
      for (int k = 0; k < 3; ++k)
        c += b2f(Wb[och * 104 + 64 + k]) * oxyz[((b * 3 + k) << 10) + n2];
      corr[nn][och] = c;
    }
  } else {                  // input-BN scale/shift from prev layer's replicated stats
    if (t < 64) {
      float a = 0.f, q = 0.f;
      #pragma unroll
      for (int rep = 0; rep < NREP; ++rep) {
        a += gsin[rep * 128 + t];
        q += gsin[rep * 128 + 64 + t];
      }
      const float invN = 1.f / (float)NPTS;
      float mean = a * invN;
      float var  = fmaxf(q * invN - mean * mean, 0.f);
      float sc = gam[t] * rsqrtf(var + 1e-5f);
      ss[t] = sc; ss[64 + t] = bet[t] - mean * sc;
    }
  }
  __syncthreads();   // wsh + ss/corr visible (only barrier before the stats epilogue)

  float scr[2][8], shr[2][8];   // per-lane BN consts, c = ks*32 + quad*8 + i
  if constexpr (!GATHER) {
    #pragma unroll
    for (int ks = 0; ks < 2; ++ks)
      #pragma unroll
      for (int i = 0; i < 8; ++i) {
        const int c = ks * 32 + quad * 8 + i;
        scr[ks][i] = ss[c]; shr[ks][i] = ss[64 + c];
      }
  }

  float s1[4] = {0.f, 0.f, 0.f, 0.f}, s2[4] = {0.f, 0.f, 0.f, 0.f};
  u32* yo = (u32*)yout;

  if constexpr (!MAXOUT) {
    const u16* bp = wsh + lr * PITCH + quad * 8;
    #pragma unroll
    for (int sub = 0; sub < 4; ++sub) {
      const int R = P0 + sub * 64 + wv * 16 + lr;
      short8 av[KSTEPS];
      if constexpr (GATHER) {
        const int id = __builtin_nontemporal_load(&nbr[R]);
        const u16* row = xsrc + (size_t)((b << 12) + id) * 64;
        uint4 a0 = *(const uint4*)(row + quad * 8);        // cached: featT has ~8x reuse
        uint4 a1 = *(const uint4*)(row + quad * 8 + 32);
        u32 w0 = 0u, w1 = 0u;
        if (quad == 0) {
          uint2 v = *(const uint2*)(xyzB + (size_t)((b << 12) + id) * 4);
          w0 = v.x; w1 = v.y;
        }
        av[0] = u4_to_s8(a0);
        av[1] = u4_to_s8(a1);
        av[2] = u4_to_s8(make_uint4(w0, w1, 0u, 0u));   // ch 64..66 = raw xyz, rest pad
      } else {
        const u16* row = xsrc + ((size_t)R << 6);
        #pragma unroll
        for (int ks = 0; ks < KSTEPS; ++ks) {
          u32x4 raw = nt_ld4(row + ks * 32 + quad * 8);   // pure stream: evict-first
          u32 w[4] = { raw[0], raw[1], raw[2], raw[3] };
          u32 o[4];
          #pragma unroll
          for (int j = 0; j < 4; ++j) {
            float lo = fmaxf(b2f((u16)(w[j] & 0xffffu)) * scr[ks][2 * j]     + shr[ks][2 * j],     0.f);
            float hi = fmaxf(b2f((u16)(w[j] >> 16))     * scr[ks][2 * j + 1] + shr[ks][2 * j + 1], 0.f);
            o[j] = pk_bf16(lo, hi);
          }
          av[ks] = u4_to_s8(make_uint4(o[0], o[1], o[2], o[3]));
        }
      }
      floatx4 acc[4];
      #pragma unroll
      for (int nt = 0; nt < 4; ++nt) acc[nt] = (floatx4){0.f, 0.f, 0.f, 0.f};
      #pragma unroll
      for (int ks = 0; ks < KSTEPS; ++ks)
        #pragma unroll
        for (int nt = 0; nt < 4; ++nt) {
          short8 bv = ld_frag8(bp + nt * 16 * PITCH + ks * 32);
          acc[nt] = __builtin_amdgcn_mfma_f32_16x16x32_bf16(av[ks], bv, acc[nt], 0, 0, 0);
        }
      const int R0 = P0 + sub * 64 + wv * 16 + quad * 4;
      float corrv[4] = {0.f, 0.f, 0.f, 0.f};
      if constexpr (GATHER) {
        const int nn = sub * 2 + (wv >> 1);     // (row>>5)&7 is constant per (sub,wv)
        #pragma unroll
        for (int nt = 0; nt < 4; ++nt) corrv[nt] = corr[nn][nt * 16 + lr];
      }
      #pragma unroll
      for (int nt = 0; nt < 4; ++nt)
        #pragma unroll
        for (int r = 0; r < 4; ++r) {
          float v = acc[nt][r] - corrv[nt];
          s1[nt] += v; s2[nt] += v * v;
          float vo = __shfl_xor(v, 1);
          if ((lr & 1) == 0)
            __builtin_nontemporal_store(pk_bf16(v, vo),
                &yo[(size_t)(R0 + r) * 32 + nt * 8 + (lr >> 1)]);
        }
    }
  } else {
    // wave = 32 rows (rg) x 64 chans (cg): max-group fully in-wave
    const int rg = wv >> 1, cg = wv & 1;
    const u16* bp = wsh + (cg * 64 + lr) * PITCH + quad * 8;
    for (int sub = 0; sub < 4; ++sub) {
      short8 av[2][2];
      #pragma unroll
      for (int h = 0; h < 2; ++h) {
        const int R = P0 + sub * 64 + rg * 32 + h * 16 + lr;
        const u16* row = xsrc + ((size_t)R << 6);
        #pragma unroll
        for (int ks = 0; ks < 2; ++ks) {
          u32x4 raw = nt_ld4(row + ks * 32 + quad * 8);
          u32 w[4] = { raw[0], raw[1], raw[2], raw[3] };
          u32 o[4];
          #pragma unroll
          for (int j = 0; j < 4; ++j) {
            float lo = fmaxf(b2f((u16)(w[j] & 0xffffu)) * scr[ks][2 * j]     + shr[ks][2 * j],     0.f);
            float hi = fmaxf(b2f((u16)(w[j] >> 16))     * scr[ks][2 * j + 1] + shr[ks][2 * j + 1], 0.f);
            o[j] = pk_bf16(lo, hi);
          }
          av[h][ks] = u4_to_s8(make_uint4(o[0], o[1], o[2], o[3]));
        }
      }
      floatx4 acc[2][4];
      #pragma unroll
      for (int h = 0; h < 2; ++h)
        #pragma unroll
        for (int nt = 0; nt < 4; ++nt) acc[h][nt] = (floatx4){0.f, 0.f, 0.f, 0.f};
      #pragma unroll
      for (int ks = 0; ks < 2; ++ks)
        #pragma unroll
        for (int nt = 0; nt < 4; ++nt) {
          short8 bv = ld_frag8(bp + nt * 16 * PITCH + ks * 32);
          #pragma unroll
          for (int h = 0; h < 2; ++h)
            acc[h][nt] = __builtin_amdgcn_mfma_f32_16x16x32_bf16(av[h][ks], bv, acc[h][nt], 0, 0, 0);
        }
      float mx[4], mn[4];
      #pragma unroll
      for (int nt = 0; nt < 4; ++nt) {
        mx[nt] = -INFINITY; mn[nt] = INFINITY;
        #pragma unroll
        for (int h = 0; h < 2; ++h)
          #pragma unroll
          for (int r = 0; r < 4; ++r) {
            float v = acc[h][nt][r];
            s1[nt] += v; s2[nt] += v * v;
            mx[nt] = fmaxf(mx[nt], v); mn[nt] = fminf(mn[nt], v);
          }
        mx[nt] = fmaxf(mx[nt], __shfl_xor(mx[nt], 16));
        mx[nt] = fmaxf(mx[nt], __shfl_xor(mx[nt], 32));
        mn[nt] = fminf(mn[nt], __shfl_xor(mn[nt], 16));
        mn[nt] = fminf(mn[nt], __shfl_xor(mn[nt], 32));
      }
      if (lane < 16) {
        const int grp = blk * 8 + sub * 2 + rg;   // b*1024 + n2
        #pragma unroll
        for (int nt = 0; nt < 4; ++nt)
          gm[(size_t)grp * 128 + cg * 64 + nt * 16 + lr] = pk_bf16(mx[nt], mn[nt]);
      }
    }
  }

  // block stats: shuffle over quads, LDS over waves, one atomic per channel
  #pragma unroll
  for (int nt = 0; nt < 4; ++nt) {
    s1[nt] += __shfl_xor(s1[nt], 16); s1[nt] += __shfl_xor(s1[nt], 32);
    s2[nt] += __shfl_xor(s2[nt], 16); s2[nt] += __shfl_xor(s2[nt], 32);
  }
  if (lane < 16) {
    #pragma unroll
    for (int nt = 0; nt < 4; ++nt) {
      red[wv * 64 + nt * 16 + lr] = s1[nt];
      red[256 + wv * 64 + nt * 16 + lr] = s2[nt];
    }
  }
  __syncthreads();
  float* gb = gsout + (blk & (NREP - 1)) * (MAXOUT ? 256 : 128);
  if constexpr (!MAXOUT) {
    if (t < 64) {
      unsafeAtomicAdd(&gb[t], red[t] + red[64 + t] + red[128 + t] + red[192 + t]);
    } else if (t < 128) {
      int c = t - 64;
      unsafeAtomicAdd(&gb[64 + c], red[256 + c] + red[320 + c] + red[384 + c] + red[448 + c]);
    }
  } else {
    // chans 0..63 on waves {0,2}; 64..127 on waves {1,3}
    if (t < 128) {
      int half = t >> 6, i = t & 63;
      unsafeAtomicAdd(&gb[t], red[half * 64 + i] + red[(half + 2) * 64 + i]);
    } else {
      int c = t - 128, half = c >> 6, i = c & 63;
      unsafeAtomicAdd(&gb[128 + c], red[256 + half * 64 + i] + red[256 + (half + 2) * 64 + i]);
    }
  }
}

// ---- final: BN2 + relu on packed max/min, transpose to [b][c][n2] ----
__global__ __launch_bounds__(256) void final_out(const u32* __restrict__ gm,
                                                 const float* __restrict__ gs,
                                                 const float* __restrict__ gam,
                                                 const float* __restrict__ bet,
                                                 float* __restrict__ out) {
  __shared__ float tile[64 * 33];
  __shared__ float ssc[128], ssh[128];
  int blk = blockIdx.x;                 // 1024 = 16 * 4 * 16
  int b = blk >> 6, rem = blk & 63, cc = rem >> 4, nn = rem & 15;
  int t = threadIdx.x;
  if (t < 128) {
    float a = 0.f, q = 0.f;
    #pragma unroll
    for (int rep = 0; rep < NREP; ++rep) {
      a += gs[rep * 256 + t];
      q += gs[rep * 256 + 128 + t];
    }
    const float invN = 1.f / (float)NPTS;
    float mean = a * invN;
    float var  = fmaxf(q * invN - mean * mean, 0.f);
    float sc = gam[t] * rsqrtf(var + 1e-5f);
    ssc[t] = sc; ssh[t] = bet[t] - mean * sc;
  }
  __syncthreads();
  #pragma unroll
  for (int i = 0; i < 8; ++i) {
    int flat = t + i * 256;             // 2048
    int n2l = flat >> 5, cl = flat & 31;
    int c = cc * 32 + cl;
    size_t idx = (size_t)((b << 10) + nn * 64 + n2l) * 128 + c;
    u32 p = gm[idx];
    float mxv = b2f((u16)(p & 0xffffu)), mnv = b2f((u16)(p >> 16));
    float scv = ssc[c], shv = ssh[c];
    float v = (scv >= 0.f) ? mxv : mnv;
    tile[n2l * 33 + cl] = fmaxf(scv * v + shv, 0.f);
  }
  __syncthreads();
  #pragma unroll
  for (int i = 0; i < 8; ++i) {
    int flat = t + i * 256;
    int cl = flat >> 6, n2l = flat & 63;
    out[(size_t)((b * 128) + cc * 32 + cl) * 1024 + nn * 64 + n2l] = tile[n2l * 33 + cl];
  }
}

extern "C" void kernel_launch(void* const* d_in, const int* in_sizes, int n_in,
                              void* d_out, int out_size, void* d_ws, size_t ws_size,
                              hipStream_t stream) {
  const float* in_xyz  = (const float*)d_in[0];
  const float* out_xyz = (const float*)d_in[1];
  const float* in_feat = (const float*)d_in[2];
  const int*   nbr     = (const int*)d_in[3];
  const float* W0 = (const float*)d_in[4];
  const float* g0 = (const float*)d_in[5];
  const float* b0 = (const float*)d_in[6];
  const float* W1 = (const float*)d_in[7];
  const float* g1 = (const float*)d_in[8];
  const float* b1 = (const float*)d_in[9];
  const float* W2 = (const float*)d_in[10];
  const float* g2 = (const float*)d_in[11];
  const float* b2 = (const float*)d_in[12];
  float* out = (float*)d_out;

  char* ws = (char*)d_ws;
  u16*    Wb    = (u16*)(ws + 4096);           // 20480 u16
  float*  gs0   = (float*)(ws + 49152);        // NREP x [64 s1 | 64 s2]
  float*  gs1   = (float*)(ws + 51200);        // NREP x [64 s1 | 64 s2]
  float*  gs2   = (float*)(ws + 53248);        // NREP x [128 s1 | 128 s2]
  u16*    featT = (u16*)(ws + 262144);         // 8 MiB
  u16*    xyzB  = (u16*)(ws + 8650752);        // 512 KiB (b,n -> 4x bf16)
  u16*    y0    = (u16*)(ws + 9699328);        // 64 MiB
  u16*    y1    = (u16*)(ws + 76808192);       // 64 MiB (end 143,917,056)
  u32*    gm    = (u32*)(ws + 9699328);        // y0 area; y0 dead after L1 (8 MiB packed)

  hipLaunchKernelGGL(prep_all, dim3(4433), dim3(256), 0, stream,
                     in_feat, in_xyz, W0, W1, W2, featT, xyzB, Wb, gs0);

  hipLaunchKernelGGL((gemm_layer<3, 64, true, false>), dim3(2048), dim3(256), 0, stream,
                     featT, xyzB, out_xyz, nbr, Wb, nullptr, nullptr, nullptr,
                     y0, nullptr, gs0);

  hipLaunchKernelGGL((gemm_layer<2, 64, false, false>), dim3(2048), dim3(256), 0, stream,
                     y0, nullptr, nullptr, nullptr, Wb + 6656, gs0, g0, b0,
                     y1, nullptr, gs1);

  hipLaunchKernelGGL((gemm_layer<2, 128, false, true>), dim3(2048), dim3(256), 0, stream,
                     y1, nullptr, nullptr, nullptr, Wb + 11264, gs1, g1, b1,
                     nullptr, gm, gs2);

  hipLaunchKernelGGL(final_out, dim3(1024), dim3(256), 0, stream, gm, gs2, g2, b2, out);
}

// Round 4
// 255.178 us; speedup vs baseline: 1.1550x; 1.1550x over previous
//
#include <hip/hip_runtime.h>
#include <cstdint>

typedef unsigned short u16;
typedef unsigned int   u32;
typedef __attribute__((ext_vector_type(8))) short  short8;
typedef __attribute__((ext_vector_type(4))) float  floatx4;
typedef __attribute__((ext_vector_type(4))) unsigned int u32x4;

#define NPTS 524288   // B*N2*K
#define NREP 4        // stat-accumulator replicas (atomic contention / NREP)

__device__ __forceinline__ float b2f(u16 h) { return __uint_as_float(((u32)h) << 16); }
__device__ __forceinline__ u16 f2b(float f) {
  u32 u = __float_as_uint(f);
  return (u16)((u + 0x7FFFu + ((u >> 16) & 1u)) >> 16);
}
__device__ __forceinline__ u32 pk_bf16(float lo, float hi) {
  return (u32)f2b(lo) | ((u32)f2b(hi) << 16);
}
__device__ __forceinline__ short8 ld_frag8(const u16* p) {
  union { uint4 q; short8 s; } x;
  x.q = *(const uint4*)p;
  return x.s;
}
__device__ __forceinline__ short8 u4_to_s8(uint4 q) {
  union { uint4 q; short8 s; } x; x.q = q; return x.s;
}
__device__ __forceinline__ u32x4 nt_ld4(const void* p) {
  return __builtin_nontemporal_load((const u32x4*)p);
}

// ---- combined prep: featT transpose + xyzB pack + W->bf16 padded + stat zero ----
// Wb layout (u16): W0 64 x pitch104 @0 (cols 67..103 zero) ; W1 64 x pitch72 @6656 ; W2 128 x pitch72 @11264
__global__ __launch_bounds__(256) void prep_all(const float* __restrict__ inf,
                                                const float* __restrict__ ixyz,
                                                const float* __restrict__ W0,
                                                const float* __restrict__ W1,
                                                const float* __restrict__ W2,
                                                u16* __restrict__ featT,
                                                u16* __restrict__ xyzB,
                                                u16* __restrict__ Wb,
                                                float* __restrict__ gz) {
  __shared__ float tile[32 * 33];
  const int bk = blockIdx.x, t = threadIdx.x;
  if (bk < 4096) {          // in_feature [b][c][n] f32 -> featT [b][n][c] bf16
    int b = bk >> 8, rem = bk & 255, cc = rem >> 7, nc = rem & 127;
    #pragma unroll
    for (int i = 0; i < 4; ++i) {
      int flat = t + i * 256;
      int cl = flat >> 5, nl = flat & 31;
      tile[cl * 33 + nl] = inf[(size_t)((b * 64) + cc * 32 + cl) * 4096 + nc * 32 + nl];
    }
    __syncthreads();
    #pragma unroll
    for (int i = 0; i < 4; ++i) {
      int flat = t + i * 256;
      int nl = flat >> 5, cl = flat & 31;
      featT[(size_t)((b << 12) + nc * 32 + nl) * 64 + cc * 32 + cl] = f2b(tile[cl * 33 + nl]);
    }
  } else if (bk < 4352) {   // in_xyz [b][3][n] -> xyzB [b][n][4xbf16] (8 B records)
    int g = (bk - 4096) * 256 + t;
    int b = g >> 12, n = g & 4095;
    const float* p = ixyz + (size_t)b * 12288;
    u32 lo = pk_bf16(p[n], p[4096 + n]);
    u32 hi = (u32)f2b(p[8192 + n]);
    *(uint2*)(xyzB + (size_t)g * 4) = make_uint2(lo, hi);
  } else if (bk < 4432) {   // weights: 20480 u16 over 80 blocks
    int s = (bk - 4352) * 256 + t;
    u16 v = 0;
    if (s < 6656)       { int o = s / 104, c = s % 104; if (c < 67) v = f2b(W0[o * 67 + c]); }
    else if (s < 11264) { int q = s - 6656;  int o = q / 72, c = q % 72; if (c < 64) v = f2b(W1[o * 64 + c]); }
    else                { int q = s - 11264; int o = q / 72, c = q % 72; if (c < 64) v = f2b(W2[o * 64 + c]); }
    Wb[s] = v;
  } else {                  // zero 2048 floats of stat accumulators (gs0|gs1|gs2)
    #pragma unroll
    for (int i = 0; i < 8; ++i) gz[t + i * 256] = 0.f;
  }
}

// ---- fused layer: direct global->reg A-fragments ----
// XCD swizzle: HW round-robins blockIdx across 8 XCDs; remap so each XCD gets a
// CONTIGUOUS logical range (2048/8=256 blocks = 2 batch values) -> per-XCD L2
// working set ~1.1 MiB (featT+xyzB) regardless of occupancy.
// GATHER layer: xyz recentering folded out: concat(f,xyz-o)@W == concat(f,xyz)@W - o@W[:,64:67]
// Stats: per-block LDS reduce -> one unsafeAtomicAdd per channel into NREP-replicated f32 buf.
template<int KSTEPS, int OCH, bool GATHER, bool MAXOUT>
__global__ __launch_bounds__(256, MAXOUT ? 4 : 5) void gemm_layer(
    const u16* __restrict__ xsrc, const u16* __restrict__ xyzB,
    const float* __restrict__ oxyz, const int* __restrict__ nbr,
    const u16* __restrict__ Wb,
    const float* __restrict__ gsin, const float* __restrict__ gam,
    const float* __restrict__ bet,
    u16* __restrict__ yout, u32* __restrict__ gm,
    float* __restrict__ gsout) {
  constexpr int PITCH = KSTEPS * 32 + 8;   // 104 / 72
  __shared__ __align__(16) u16 wsh[OCH * PITCH];
  __shared__ float red[512];
  __shared__ float ss[GATHER ? 4 : 128];
  __shared__ float corr[GATHER ? 8 : 1][64];

  const int t = threadIdx.x;
  const int blk = (blockIdx.x & 7) * 256 + (blockIdx.x >> 3);   // XCD-contiguous
  const int lane = t & 63, wv = t >> 6, lr = lane & 15, quad = lane >> 4;
  const int P0 = blk * 256;
  const int b = blk >> 7;

  { // W -> LDS (bf16, padded pitch)
    const u32* src = (const u32*)Wb;
    u32* dst = (u32*)wsh;
    constexpr int NW = OCH * PITCH / 2;
    #pragma unroll
    for (int i = 0; i < NW / 256; ++i) dst[t + i * 256] = src[t + i * 256];
  }
  if constexpr (GATHER) {   // oxyz @ W[:,64:67] correction table: 8 n2 x 64 och
    #pragma unroll
    for (int half = 0; half < 2; ++half) {
      int e = t + half * 256, nn = e >> 6, och = e & 63;
      int n2 = (blk * 8 + nn) & 1023;
      float c = 0.f;
      #pragma unroll
      for (int k = 0; k < 3; ++k)
        c += b2f(Wb[och * 104 + 64 + k]) * oxyz[((b * 3 + k) << 10) + n2];
      corr[nn][och] = c;
    }
  } else {                  // input-BN scale/shift from prev layer's replicated stats
    if (t < 64) {
      float a = 0.f, q = 0.f;
      #pragma unroll
      for (int rep = 0; rep < NREP; ++rep) {
        a += gsin[rep * 128 + t];
        q += gsin[rep * 128 + 64 + t];
      }
      const float invN = 1.f / (float)NPTS;
      float mean = a * invN;
      float var  = fmaxf(q * invN - mean * mean, 0.f);
      float sc = gam[t] * rsqrtf(var + 1e-5f);
      ss[t] = sc; ss[64 + t] = bet[t] - mean * sc;
    }
  }
  __syncthreads();   // wsh + ss/corr visible (only barrier before the stats epilogue)

  float scr[2][8], shr[2][8];   // per-lane BN consts, c = ks*32 + quad*8 + i
  if constexpr (!GATHER) {
    #pragma unroll
    for (int ks = 0; ks < 2; ++ks)
      #pragma unroll
      for (int i = 0; i < 8; ++i) {
        const int c = ks * 32 + quad * 8 + i;
        scr[ks][i] = ss[c]; shr[ks][i] = ss[64 + c];
      }
  }

  float s1[4] = {0.f, 0.f, 0.f, 0.f}, s2[4] = {0.f, 0.f, 0.f, 0.f};
  u32* yo = (u32*)yout;

  if constexpr (!MAXOUT) {
    const u16* bp = wsh + lr * PITCH + quad * 8;
    #pragma unroll
    for (int sub = 0; sub < 4; ++sub) {
      const int R = P0 + sub * 64 + wv * 16 + lr;
      short8 av[KSTEPS];
      if constexpr (GATHER) {
        const int id = __builtin_nontemporal_load(&nbr[R]);
        const u16* row = xsrc + (size_t)((b << 12) + id) * 64;
        uint4 a0 = *(const uint4*)(row + quad * 8);        // cached: featT L2-resident
        uint4 a1 = *(const uint4*)(row + quad * 8 + 32);
        u32 w0 = 0u, w1 = 0u;
        if (quad == 0) {
          uint2 v = *(const uint2*)(xyzB + (size_t)((b << 12) + id) * 4);
          w0 = v.x; w1 = v.y;
        }
        av[0] = u4_to_s8(a0);
        av[1] = u4_to_s8(a1);
        av[2] = u4_to_s8(make_uint4(w0, w1, 0u, 0u));   // ch 64..66 = raw xyz, rest pad
      } else {
        const u16* row = xsrc + ((size_t)R << 6);
        #pragma unroll
        for (int ks = 0; ks < KSTEPS; ++ks) {
          u32x4 raw = nt_ld4(row + ks * 32 + quad * 8);   // pure stream read: evict-first
          u32 w[4] = { raw[0], raw[1], raw[2], raw[3] };
          u32 o[4];
          #pragma unroll
          for (int j = 0; j < 4; ++j) {
            float lo = fmaxf(b2f((u16)(w[j] & 0xffffu)) * scr[ks][2 * j]     + shr[ks][2 * j],     0.f);
            float hi = fmaxf(b2f((u16)(w[j] >> 16))     * scr[ks][2 * j + 1] + shr[ks][2 * j + 1], 0.f);
            o[j] = pk_bf16(lo, hi);
          }
          av[ks] = u4_to_s8(make_uint4(o[0], o[1], o[2], o[3]));
        }
      }
      floatx4 acc[4];
      #pragma unroll
      for (int nt = 0; nt < 4; ++nt) acc[nt] = (floatx4){0.f, 0.f, 0.f, 0.f};
      #pragma unroll
      for (int ks = 0; ks < KSTEPS; ++ks)
        #pragma unroll
        for (int nt = 0; nt < 4; ++nt) {
          short8 bv = ld_frag8(bp + nt * 16 * PITCH + ks * 32);
          acc[nt] = __builtin_amdgcn_mfma_f32_16x16x32_bf16(av[ks], bv, acc[nt], 0, 0, 0);
        }
      const int R0 = P0 + sub * 64 + wv * 16 + quad * 4;
      float corrv[4] = {0.f, 0.f, 0.f, 0.f};
      if constexpr (GATHER) {
        const int nn = sub * 2 + (wv >> 1);     // (row>>5)&7 is constant per (sub,wv)
        #pragma unroll
        for (int nt = 0; nt < 4; ++nt) corrv[nt] = corr[nn][nt * 16 + lr];
      }
      #pragma unroll
      for (int nt = 0; nt < 4; ++nt)
        #pragma unroll
        for (int r = 0; r < 4; ++r) {
          float v = acc[nt][r] - corrv[nt];
          s1[nt] += v; s2[nt] += v * v;
          float vo = __shfl_xor(v, 1);
          if ((lr & 1) == 0)
            yo[(size_t)(R0 + r) * 32 + nt * 8 + (lr >> 1)] = pk_bf16(v, vo);
        }
    }
  } else {
    // wave = 32 rows (rg) x 64 chans (cg): max-group fully in-wave
    const int rg = wv >> 1, cg = wv & 1;
    const u16* bp = wsh + (cg * 64 + lr) * PITCH + quad * 8;
    for (int sub = 0; sub < 4; ++sub) {
      short8 av[2][2];
      #pragma unroll
      for (int h = 0; h < 2; ++h) {
        const int R = P0 + sub * 64 + rg * 32 + h * 16 + lr;
        const u16* row = xsrc + ((size_t)R << 6);
        #pragma unroll
        for (int ks = 0; ks < 2; ++ks) {
          u32x4 raw = nt_ld4(row + ks * 32 + quad * 8);
          u32 w[4] = { raw[0], raw[1], raw[2], raw[3] };
          u32 o[4];
          #pragma unroll
          for (int j = 0; j < 4; ++j) {
            float lo = fmaxf(b2f((u16)(w[j] & 0xffffu)) * scr[ks][2 * j]     + shr[ks][2 * j],     0.f);
            float hi = fmaxf(b2f((u16)(w[j] >> 16))     * scr[ks][2 * j + 1] + shr[ks][2 * j + 1], 0.f);
            o[j] = pk_bf16(lo, hi);
          }
          av[h][ks] = u4_to_s8(make_uint4(o[0], o[1], o[2], o[3]));
        }
      }
      floatx4 acc[2][4];
      #pragma unroll
      for (int h = 0; h < 2; ++h)
        #pragma unroll
        for (int nt = 0; nt < 4; ++nt) acc[h][nt] = (floatx4){0.f, 0.f, 0.f, 0.f};
      #pragma unroll
      for (int ks = 0; ks < 2; ++ks)
        #pragma unroll
        for (int nt = 0; nt < 4; ++nt) {
          short8 bv = ld_frag8(bp + nt * 16 * PITCH + ks * 32);
          #pragma unroll
          for (int h = 0; h < 2; ++h)
            acc[h][nt] = __builtin_amdgcn_mfma_f32_16x16x32_bf16(av[h][ks], bv, acc[h][nt], 0, 0, 0);
        }
      float mx[4], mn[4];
      #pragma unroll
      for (int nt = 0; nt < 4; ++nt) {
        mx[nt] = -INFINITY; mn[nt] = INFINITY;
        #pragma unroll
        for (int h = 0; h < 2; ++h)
          #pragma unroll
          for (int r = 0; r < 4; ++r) {
            float v = acc[h][nt][r];
            s1[nt] += v; s2[nt] += v * v;
            mx[nt] = fmaxf(mx[nt], v); mn[nt] = fminf(mn[nt], v);
          }
        mx[nt] = fmaxf(mx[nt], __shfl_xor(mx[nt], 16));
        mx[nt] = fmaxf(mx[nt], __shfl_xor(mx[nt], 32));
        mn[nt] = fminf(mn[nt], __shfl_xor(mn[nt], 16));
        mn[nt] = fminf(mn[nt], __shfl_xor(mn[nt], 32));
      }
      if (lane < 16) {
        const int grp = blk * 8 + sub * 2 + rg;   // b*1024 + n2
        #pragma unroll
        for (int nt = 0; nt < 4; ++nt)
          gm[(size_t)grp * 128 + cg * 64 + nt * 16 + lr] = pk_bf16(mx[nt], mn[nt]);
      }
    }
  }

  // block stats: shuffle over quads, LDS over waves, one atomic per channel
  #pragma unroll
  for (int nt = 0; nt < 4; ++nt) {
    s1[nt] += __shfl_xor(s1[nt], 16); s1[nt] += __shfl_xor(s1[nt], 32);
    s2[nt] += __shfl_xor(s2[nt], 16); s2[nt] += __shfl_xor(s2[nt], 32);
  }
  if (lane < 16) {
    #pragma unroll
    for (int nt = 0; nt < 4; ++nt) {
      red[wv * 64 + nt * 16 + lr] = s1[nt];
      red[256 + wv * 64 + nt * 16 + lr] = s2[nt];
    }
  }
  __syncthreads();
  float* gb = gsout + (blk & (NREP - 1)) * (MAXOUT ? 256 : 128);
  if constexpr (!MAXOUT) {
    if (t < 64) {
      unsafeAtomicAdd(&gb[t], red[t] + red[64 + t] + red[128 + t] + red[192 + t]);
    } else if (t < 128) {
      int c = t - 64;
      unsafeAtomicAdd(&gb[64 + c], red[256 + c] + red[320 + c] + red[384 + c] + red[448 + c]);
    }
  } else {
    // chans 0..63 on waves {0,2}; 64..127 on waves {1,3}
    if (t < 128) {
      int half = t >> 6, i = t & 63;
      unsafeAtomicAdd(&gb[t], red[half * 64 + i] + red[(half + 2) * 64 + i]);
    } else {
      int c = t - 128, half = c >> 6, i = c & 63;
      unsafeAtomicAdd(&gb[128 + c], red[256 + half * 64 + i] + red[256 + (half + 2) * 64 + i]);
    }
  }
}

// ---- final: BN2 + relu on packed max/min, transpose to [b][c][n2] ----
__global__ __launch_bounds__(256) void final_out(const u32* __restrict__ gm,
                                                 const float* __restrict__ gs,
                                                 const float* __restrict__ gam,
                                                 const float* __restrict__ bet,
                                                 float* __restrict__ out) {
  __shared__ float tile[64 * 33];
  __shared__ float ssc[128], ssh[128];
  int blk = blockIdx.x;                 // 1024 = 16 * 4 * 16
  int b = blk >> 6, rem = blk & 63, cc = rem >> 4, nn = rem & 15;
  int t = threadIdx.x;
  if (t < 128) {
    float a = 0.f, q = 0.f;
    #pragma unroll
    for (int rep = 0; rep < NREP; ++rep) {
      a += gs[rep * 256 + t];
      q += gs[rep * 256 + 128 + t];
    }
    const float invN = 1.f / (float)NPTS;
    float mean = a * invN;
    float var  = fmaxf(q * invN - mean * mean, 0.f);
    float sc = gam[t] * rsqrtf(var + 1e-5f);
    ssc[t] = sc; ssh[t] = bet[t] - mean * sc;
  }
  __syncthreads();
  #pragma unroll
  for (int i = 0; i < 8; ++i) {
    int flat = t + i * 256;             // 2048
    int n2l = flat >> 5, cl = flat & 31;
    int c = cc * 32 + cl;
    size_t idx = (size_t)((b << 10) + nn * 64 + n2l) * 128 + c;
    u32 p = gm[idx];
    float mxv = b2f((u16)(p & 0xffffu)), mnv = b2f((u16)(p >> 16));
    float scv = ssc[c], shv = ssh[c];
    float v = (scv >= 0.f) ? mxv : mnv;
    tile[n2l * 33 + cl] = fmaxf(scv * v + shv, 0.f);
  }
  __syncthreads();
  #pragma unroll
  for (int i = 0; i < 8; ++i) {
    int flat = t + i * 256;
    int cl = flat >> 6, n2l = flat & 63;
    out[(size_t)((b * 128) + cc * 32 + cl) * 1024 + nn * 64 + n2l] = tile[n2l * 33 + cl];
  }
}

extern "C" void kernel_launch(void* const* d_in, const int* in_sizes, int n_in,
                              void* d_out, int out_size, void* d_ws, size_t ws_size,
                              hipStream_t stream) {
  const float* in_xyz  = (const float*)d_in[0];
  const float* out_xyz = (const float*)d_in[1];
  const float* in_feat = (const float*)d_in[2];
  const int*   nbr     = (const int*)d_in[3];
  const float* W0 = (const float*)d_in[4];
  const float* g0 = (const float*)d_in[5];
  const float* b0 = (const float*)d_in[6];
  const float* W1 = (const float*)d_in[7];
  const float* g1 = (const float*)d_in[8];
  const float* b1 = (const float*)d_in[9];
  const float* W2 = (const float*)d_in[10];
  const float* g2 = (const float*)d_in[11];
  const float* b2 = (const float*)d_in[12];
  float* out = (float*)d_out;

  char* ws = (char*)d_ws;
  u16*    Wb    = (u16*)(ws + 4096);           // 20480 u16
  float*  gs0   = (float*)(ws + 49152);        // NREP x [64 s1 | 64 s2]
  float*  gs1   = (float*)(ws + 51200);        // NREP x [64 s1 | 64 s2]
  float*  gs2   = (float*)(ws + 53248);        // NREP x [128 s1 | 128 s2]
  u16*    featT = (u16*)(ws + 262144);         // 8 MiB
  u16*    xyzB  = (u16*)(ws + 8650752);        // 512 KiB (b,n -> 4x bf16)
  u16*    y0    = (u16*)(ws + 9699328);        // 64 MiB
  u16*    y1    = (u16*)(ws + 76808192);       // 64 MiB (end 143,917,056)
  u32*    gm    = (u32*)(ws + 9699328);        // y0 area; y0 dead after L1 (8 MiB packed)

  hipLaunchKernelGGL(prep_all, dim3(4433), dim3(256), 0, stream,
                     in_feat, in_xyz, W0, W1, W2, featT, xyzB, Wb, gs0);

  hipLaunchKernelGGL((gemm_layer<3, 64, true, false>), dim3(2048), dim3(256), 0, stream,
                     featT, xyzB, out_xyz, nbr, Wb, nullptr, nullptr, nullptr,
                     y0, nullptr, gs0);

  hipLaunchKernelGGL((gemm_layer<2, 64, false, false>), dim3(2048), dim3(256), 0, stream,
                     y0, nullptr, nullptr, nullptr, Wb + 6656, gs0, g0, b0,
                     y1, nullptr, gs1);

  hipLaunchKernelGGL((gemm_layer<2, 128, false, true>), dim3(2048), dim3(256), 0, stream,
                     y1, nullptr, nullptr, nullptr, Wb + 11264, gs1, g1, b1,
                     nullptr, gm, gs2);

  hipLaunchKernelGGL(final_out, dim3(1024), dim3(256), 0, stream, gm, gs2, g2, b2, out);
}

// Round 7
// 214.943 us; speedup vs baseline: 1.3712x; 1.1872x over previous
//
#include <hip/hip_runtime.h>
#include <cstdint>

typedef unsigned short u16;
typedef unsigned int   u32;
typedef __attribute__((ext_vector_type(8))) short  short8;
typedef __attribute__((ext_vector_type(4))) float  floatx4;
typedef __attribute__((ext_vector_type(4))) unsigned int u32x4;

#define NPTS 524288   // B*N2*K
#define NREP 4        // stat-accumulator replicas (atomic contention / NREP)

__device__ __forceinline__ float b2f(u16 h) { return __uint_as_float(((u32)h) << 16); }
__device__ __forceinline__ u16 f2b(float f) {
  u32 u = __float_as_uint(f);
  return (u16)((u + 0x7FFFu + ((u >> 16) & 1u)) >> 16);
}
__device__ __forceinline__ u32 pk_bf16(float lo, float hi) {
  return (u32)f2b(lo) | ((u32)f2b(hi) << 16);
}
__device__ __forceinline__ short8 ld_frag8(const u16* p) {
  union { uint4 q; short8 s; } x;
  x.q = *(const uint4*)p;
  return x.s;
}
__device__ __forceinline__ short8 u4_to_s8(uint4 q) {
  union { uint4 q; short8 s; } x; x.q = q; return x.s;
}
__device__ __forceinline__ u32x4 nt_ld4(const void* p) {
  return __builtin_nontemporal_load((const u32x4*)p);
}

// ---- combined prep (round-4 proven version): featT transpose + xyzB pack + W->bf16 + stat zero ----
// Wb layout (u16): W0 64 x pitch104 @0 (cols 67..103 zero) ; W1 64 x pitch72 @6656 ; W2 128 x pitch72 @11264
__global__ __launch_bounds__(256) void prep_all(const float* __restrict__ inf,
                                                const float* __restrict__ ixyz,
                                                const float* __restrict__ W0,
                                                const float* __restrict__ W1,
                                                const float* __restrict__ W2,
                                                u16* __restrict__ featT,
                                                u16* __restrict__ xyzB,
                                                u16* __restrict__ Wb,
                                                float* __restrict__ gz) {
  __shared__ float tile[32 * 33];
  const int bk = blockIdx.x, t = threadIdx.x;
  if (bk < 4096) {          // in_feature [b][c][n] f32 -> featT [b][n][c] bf16
    int b = bk >> 8, rem = bk & 255, cc = rem >> 7, nc = rem & 127;
    #pragma unroll
    for (int i = 0; i < 4; ++i) {
      int flat = t + i * 256;
      int cl = flat >> 5, nl = flat & 31;
      tile[cl * 33 + nl] = inf[(size_t)((b * 64) + cc * 32 + cl) * 4096 + nc * 32 + nl];
    }
    __syncthreads();
    #pragma unroll
    for (int i = 0; i < 4; ++i) {
      int flat = t + i * 256;
      int nl = flat >> 5, cl = flat & 31;
      featT[(size_t)((b << 12) + nc * 32 + nl) * 64 + cc * 32 + cl] = f2b(tile[cl * 33 + nl]);
    }
  } else if (bk < 4352) {   // in_xyz [b][3][n] -> xyzB [b][n][4xbf16] (8 B records)
    int g = (bk - 4096) * 256 + t;
    int b = g >> 12, n = g & 4095;
    const float* p = ixyz + (size_t)b * 12288;
    u32 lo = pk_bf16(p[n], p[4096 + n]);
    u32 hi = (u32)f2b(p[8192 + n]);
    *(uint2*)(xyzB + (size_t)g * 4) = make_uint2(lo, hi);
  } else if (bk < 4432) {   // weights: 20480 u16 over 80 blocks
    int s = (bk - 4352) * 256 + t;
    u16 v = 0;
    if (s < 6656)       { int o = s / 104, c = s % 104; if (c < 67) v = f2b(W0[o * 67 + c]); }
    else if (s < 11264) { int q = s - 6656;  int o = q / 72, c = q % 72; if (c < 64) v = f2b(W1[o * 64 + c]); }
    else                { int q = s - 11264; int o = q / 72, c = q % 72; if (c < 64) v = f2b(W2[o * 64 + c]); }
    Wb[s] = v;
  } else {                  // zero 2048 floats of stat accumulators (gs0|gs1|gs2)
    #pragma unroll
    for (int i = 0; i < 8; ++i) gz[t + i * 256] = 0.f;
  }
}

// ---- fused layer: direct global->reg A-fragments, block-cooperative full-line stores ----
// XCD swizzle: contiguous 256-block range per XCD -> per-XCD L2 hot set ~1.1 MiB.
// GATHER: recentering folded out: concat(f,xyz-o)@W == concat(f,xyz)@W - o@W[:,64:67]
// Epilogue: all waves stage the 64x64ch sub-tile into LDS [64][36] u32, barrier,
//   256 threads store 64 full 128 B lines (NT), barrier. No RFO, no write amplification.
// Stats: per-block LDS reduce -> one unsafeAtomicAdd per channel (NREP-replicated).
template<int KSTEPS, int OCH, bool GATHER, bool MAXOUT>
__global__ __launch_bounds__(256, MAXOUT ? 4 : 5) void gemm_layer(
    const u16* __restrict__ xsrc, const u16* __restrict__ xyzB,
    const float* __restrict__ oxyz, const int* __restrict__ nbr,
    const u16* __restrict__ Wb,
    const float* __restrict__ gsin, const float* __restrict__ gam,
    const float* __restrict__ bet,
    u16* __restrict__ yout, u32* __restrict__ gm,
    float* __restrict__ gsout) {
  constexpr int PITCH = KSTEPS * 32 + 8;   // 104 / 72
  __shared__ __align__(16) u16 wsh[OCH * PITCH];
  __shared__ float red[512];
  __shared__ float ss[GATHER ? 4 : 128];
  __shared__ float corr[GATHER ? 8 : 1][64];
  __shared__ __align__(16) u32 xt[MAXOUT ? 256 : 2304];   // 64 rows x 36 u32 / 4x64 u32

  const int t = threadIdx.x;
  const int blk = (blockIdx.x & 7) * 256 + (blockIdx.x >> 3);   // XCD-contiguous
  const int lane = t & 63, wv = t >> 6, lr = lane & 15, quad = lane >> 4;
  const int P0 = blk * 256;
  const int b = blk >> 7;

  { // W -> LDS (bf16, padded pitch)
    const u32* src = (const u32*)Wb;
    u32* dst = (u32*)wsh;
    constexpr int NW = OCH * PITCH / 2;
    #pragma unroll
    for (int i = 0; i < NW / 256; ++i) dst[t + i * 256] = src[t + i * 256];
  }
  if constexpr (GATHER) {   // oxyz @ W[:,64:67] correction table: 8 n2 x 64 och
    #pragma unroll
    for (int half = 0; half < 2; ++half) {
      int e = t + half * 256, nn = e >> 6, och = e & 63;
      int n2 = (blk * 8 + nn) & 1023;
      float c = 0.f;
      #pragma unroll
      for (int k = 0; k < 3; ++k)
        c += b2f(Wb[och * 104 + 64 + k]) * oxyz[((b * 3 + k) << 10) + n2];
      corr[nn][och] = c;
    }
  } else {                  // input-BN scale/shift from prev layer's replicated stats
    if (t < 64) {
      float a = 0.f, q = 0.f;
      #pragma unroll
      for (int rep = 0; rep < NREP; ++rep) {
        a += gsin[rep * 128 + t];
        q += gsin[rep * 128 + 64 + t];
      }
      const float invN = 1.f / (float)NPTS;
      float mean = a * invN;
      float var  = fmaxf(q * invN - mean * mean, 0.f);
      float sc = gam[t] * rsqrtf(var + 1e-5f);
      ss[t] = sc; ss[64 + t] = bet[t] - mean * sc;
    }
  }
  __syncthreads();   // wsh + ss/corr visible

  float scr[2][8], shr[2][8];   // per-lane BN consts, c = ks*32 + quad*8 + i
  if constexpr (!GATHER) {
    #pragma unroll
    for (int ks = 0; ks < 2; ++ks)
      #pragma unroll
      for (int i = 0; i < 8; ++i) {
        const int c = ks * 32 + quad * 8 + i;
        scr[ks][i] = ss[c]; shr[ks][i] = ss[64 + c];
      }
  }

  float s1[4] = {0.f, 0.f, 0.f, 0.f}, s2[4] = {0.f, 0.f, 0.f, 0.f};
  u32* yo = (u32*)yout;

  if constexpr (!MAXOUT) {
    const u16* bp = wsh + lr * PITCH + quad * 8;
    #pragma unroll
    for (int sub = 0; sub < 4; ++sub) {
      const int R = P0 + sub * 64 + wv * 16 + lr;
      short8 av[KSTEPS];
      if constexpr (GATHER) {
        const int id = __builtin_nontemporal_load(&nbr[R]);
        const u16* row = xsrc + (size_t)((b << 12) + id) * 64;
        uint4 a0 = *(const uint4*)(row + quad * 8);        // cached: featT L2-resident
        uint4 a1 = *(const uint4*)(row + quad * 8 + 32);
        u32 w0 = 0u, w1 = 0u;
        if (quad == 0) {
          uint2 v = *(const uint2*)(xyzB + (size_t)((b << 12) + id) * 4);
          w0 = v.x; w1 = v.y;
        }
        av[0] = u4_to_s8(a0);
        av[1] = u4_to_s8(a1);
        av[2] = u4_to_s8(make_uint4(w0, w1, 0u, 0u));   // ch 64..66 = raw xyz, rest pad
      } else {
        const u16* row = xsrc + ((size_t)R << 6);
        #pragma unroll
        for (int ks = 0; ks < KSTEPS; ++ks) {
          u32x4 raw = nt_ld4(row + ks * 32 + quad * 8);   // pure stream read: evict-first
          u32 w[4] = { raw[0], raw[1], raw[2], raw[3] };
          u32 o[4];
          #pragma unroll
          for (int j = 0; j < 4; ++j) {
            float lo = fmaxf(b2f((u16)(w[j] & 0xffffu)) * scr[ks][2 * j]     + shr[ks][2 * j],     0.f);
            float hi = fmaxf(b2f((u16)(w[j] >> 16))     * scr[ks][2 * j + 1] + shr[ks][2 * j + 1], 0.f);
            o[j] = pk_bf16(lo, hi);
          }
          av[ks] = u4_to_s8(make_uint4(o[0], o[1], o[2], o[3]));
        }
      }
      floatx4 acc[4];
      #pragma unroll
      for (int nt = 0; nt < 4; ++nt) acc[nt] = (floatx4){0.f, 0.f, 0.f, 0.f};
      #pragma unroll
      for (int ks = 0; ks < KSTEPS; ++ks)
        #pragma unroll
        for (int nt = 0; nt < 4; ++nt) {
          short8 bv = ld_frag8(bp + nt * 16 * PITCH + ks * 32);
          acc[nt] = __builtin_amdgcn_mfma_f32_16x16x32_bf16(av[ks], bv, acc[nt], 0, 0, 0);
        }
      float corrv[4] = {0.f, 0.f, 0.f, 0.f};
      if constexpr (GATHER) {
        const int nn = sub * 2 + (wv >> 1);     // (row>>5)&7 is constant per (sub,wv)
        #pragma unroll
        for (int nt = 0; nt < 4; ++nt) corrv[nt] = corr[nn][nt * 16 + lr];
      }
      // stage 64-row sub-tile into block LDS [64][36] u32
      #pragma unroll
      for (int nt = 0; nt < 4; ++nt)
        #pragma unroll
        for (int r = 0; r < 4; ++r) {
          float v = acc[nt][r] - corrv[nt];
          s1[nt] += v; s2[nt] += v * v;
          float vo = __shfl_xor(v, 1);
          if ((lr & 1) == 0)
            xt[(wv * 16 + quad * 4 + r) * 36 + nt * 8 + (lr >> 1)] = pk_bf16(v, vo);
        }
      __syncthreads();   // all 64 rows staged
      // 256 threads store 64 full 128 B lines (NT): 2048 u32 = 8 u32/thread
      #pragma unroll
      for (int j = 0; j < 2; ++j) {
        int flat = t + j * 256;              // 512 = 64 rows x 8 col4
        int rowb = flat >> 3, c4 = flat & 7;
        u32x4 q = *(const u32x4*)&xt[rowb * 36 + c4 * 4];
        __builtin_nontemporal_store(q, (u32x4*)&yo[(size_t)(P0 + sub * 64 + rowb) * 32 + c4 * 4]);
      }
      __syncthreads();   // reads complete before next sub overwrites xt
    }
  } else {
    // wave = 32 rows (rg) x 64 chans (cg): max-group fully in-wave
    const int rg = wv >> 1, cg = wv & 1;
    const u16* bp = wsh + (cg * 64 + lr) * PITCH + quad * 8;
    u32* gmt = xt + wv * 64;
    for (int sub = 0; sub < 4; ++sub) {
      short8 av[2][2];
      #pragma unroll
      for (int h = 0; h < 2; ++h) {
        const int R = P0 + sub * 64 + rg * 32 + h * 16 + lr;
        const u16* row = xsrc + ((size_t)R << 6);
        #pragma unroll
        for (int ks = 0; ks < 2; ++ks) {
          u32x4 raw = nt_ld4(row + ks * 32 + quad * 8);
          u32 w[4] = { raw[0], raw[1], raw[2], raw[3] };
          u32 o[4];
          #pragma unroll
          for (int j = 0; j < 4; ++j) {
            float lo = fmaxf(b2f((u16)(w[j] & 0xffffu)) * scr[ks][2 * j]     + shr[ks][2 * j],     0.f);
            float hi = fmaxf(b2f((u16)(w[j] >> 16))     * scr[ks][2 * j + 1] + shr[ks][2 * j + 1], 0.f);
            o[j] = pk_bf16(lo, hi);
          }
          av[h][ks] = u4_to_s8(make_uint4(o[0], o[1], o[2], o[3]));
        }
      }
      floatx4 acc[2][4];
      #pragma unroll
      for (int h = 0; h < 2; ++h)
        #pragma unroll
        for (int nt = 0; nt < 4; ++nt) acc[h][nt] = (floatx4){0.f, 0.f, 0.f, 0.f};
      #pragma unroll
      for (int ks = 0; ks < 2; ++ks)
        #pragma unroll
        for (int nt = 0; nt < 4; ++nt) {
          short8 bv = ld_frag8(bp + nt * 16 * PITCH + ks * 32);
          #pragma unroll
          for (int h = 0; h < 2; ++h)
            acc[h][nt] = __builtin_amdgcn_mfma_f32_16x16x32_bf16(av[h][ks], bv, acc[h][nt], 0, 0, 0);
        }
      float mx[4], mn[4];
      #pragma unroll
      for (int nt = 0; nt < 4; ++nt) {
        mx[nt] = -INFINITY; mn[nt] = INFINITY;
        #pragma unroll
        for (int h = 0; h < 2; ++h)
          #pragma unroll
          for (int r = 0; r < 4; ++r) {
            float v = acc[h][nt][r];
            s1[nt] += v; s2[nt] += v * v;
            mx[nt] = fmaxf(mx[nt], v); mn[nt] = fminf(mn[nt], v);
          }
        mx[nt] = fmaxf(mx[nt], __shfl_xor(mx[nt], 16));
        mx[nt] = fmaxf(mx[nt], __shfl_xor(mx[nt], 32));
        mn[nt] = fminf(mn[nt], __shfl_xor(mn[nt], 16));
        mn[nt] = fminf(mn[nt], __shfl_xor(mn[nt], 32));
      }
      // stage 64 u32 per wave in LDS, barrier, coalesced 256 B store
      if (lane < 16) {
        #pragma unroll
        for (int nt = 0; nt < 4; ++nt)
          gmt[nt * 16 + lane] = pk_bf16(mx[nt], mn[nt]);
      }
      __syncthreads();
      const int grp = blk * 8 + sub * 2 + rg;   // b*1024 + n2
      gm[(size_t)grp * 128 + cg * 64 + lane] = gmt[lane];
      __syncthreads();
    }
  }

  // block stats: shuffle over quads, LDS over waves, one atomic per channel
  #pragma unroll
  for (int nt = 0; nt < 4; ++nt) {
    s1[nt] += __shfl_xor(s1[nt], 16); s1[nt] += __shfl_xor(s1[nt], 32);
    s2[nt] += __shfl_xor(s2[nt], 16); s2[nt] += __shfl_xor(s2[nt], 32);
  }
  if (lane < 16) {
    #pragma unroll
    for (int nt = 0; nt < 4; ++nt) {
      red[wv * 64 + nt * 16 + lr] = s1[nt];
      red[256 + wv * 64 + nt * 16 + lr] = s2[nt];
    }
  }
  __syncthreads();
  float* gb = gsout + (blk & (NREP - 1)) * (MAXOUT ? 256 : 128);
  if constexpr (!MAXOUT) {
    if (t < 64) {
      unsafeAtomicAdd(&gb[t], red[t] + red[64 + t] + red[128 + t] + red[192 + t]);
    } else if (t < 128) {
      int c = t - 64;
      unsafeAtomicAdd(&gb[64 + c], red[256 + c] + red[320 + c] + red[384 + c] + red[448 + c]);
    }
  } else {
    // chans 0..63 on waves {0,2}; 64..127 on waves {1,3}
    if (t < 128) {
      int half = t >> 6, i = t & 63;
      unsafeAtomicAdd(&gb[t], red[half * 64 + i] + red[(half + 2) * 64 + i]);
    } else {
      int c = t - 128, half = c >> 6, i = c & 63;
      unsafeAtomicAdd(&gb[128 + c], red[256 + half * 64 + i] + red[256 + (half + 2) * 64 + i]);
    }
  }
}

// ---- final: BN2 + relu on packed max/min, transpose to [b][c][n2] ----
__global__ __launch_bounds__(256) void final_out(const u32* __restrict__ gm,
                                                 const float* __restrict__ gs,
                                                 const float* __restrict__ gam,
                                                 const float* __restrict__ bet,
                                                 float* __restrict__ out) {
  __shared__ float tile[64 * 33];
  __shared__ float ssc[128], ssh[128];
  int blk = blockIdx.x;                 // 1024 = 16 * 4 * 16
  int b = blk >> 6, rem = blk & 63, cc = rem >> 4, nn = rem & 15;
  int t = threadIdx.x;
  if (t < 128) {
    float a = 0.f, q = 0.f;
    #pragma unroll
    for (int rep = 0; rep < NREP; ++rep) {
      a += gs[rep * 256 + t];
      q += gs[rep * 256 + 128 + t];
    }
    const float invN = 1.f / (float)NPTS;
    float mean = a * invN;
    float var  = fmaxf(q * invN - mean * mean, 0.f);
    float sc = gam[t] * rsqrtf(var + 1e-5f);
    ssc[t] = sc; ssh[t] = bet[t] - mean * sc;
  }
  __syncthreads();
  #pragma unroll
  for (int i = 0; i < 8; ++i) {
    int flat = t + i * 256;             // 2048
    int n2l = flat >> 5, cl = flat & 31;
    int c = cc * 32 + cl;
    size_t idx = (size_t)((b << 10) + nn * 64 + n2l) * 128 + c;
    u32 p = gm[idx];
    float mxv = b2f((u16)(p & 0xffffu)), mnv = b2f((u16)(p >> 16));
    float scv = ssc[c], shv = ssh[c];
    float v = (scv >= 0.f) ? mxv : mnv;
    tile[n2l * 33 + cl] = fmaxf(scv * v + shv, 0.f);
  }
  __syncthreads();
  #pragma unroll
  for (int i = 0; i < 8; ++i) {
    int flat = t + i * 256;
    int cl = flat >> 6, n2l = flat & 63;
    out[(size_t)((b * 128) + cc * 32 + cl) * 1024 + nn * 64 + n2l] = tile[n2l * 33 + cl];
  }
}

extern "C" void kernel_launch(void* const* d_in, const int* in_sizes, int n_in,
                              void* d_out, int out_size, void* d_ws, size_t ws_size,
                              hipStream_t stream) {
  const float* in_xyz  = (const float*)d_in[0];
  const float* out_xyz = (const float*)d_in[1];
  const float* in_feat = (const float*)d_in[2];
  const int*   nbr     = (const int*)d_in[3];
  const float* W0 = (const float*)d_in[4];
  const float* g0 = (const float*)d_in[5];
  const float* b0 = (const float*)d_in[6];
  const float* W1 = (const float*)d_in[7];
  const float* g1 = (const float*)d_in[8];
  const float* b1 = (const float*)d_in[9];
  const float* W2 = (const float*)d_in[10];
  const float* g2 = (const float*)d_in[11];
  const float* b2 = (const float*)d_in[12];
  float* out = (float*)d_out;

  char* ws = (char*)d_ws;
  u16*    Wb    = (u16*)(ws + 4096);           // 20480 u16
  float*  gs0   = (float*)(ws + 49152);        // NREP x [64 s1 | 64 s2]
  float*  gs1   = (float*)(ws + 51200);        // NREP x [64 s1 | 64 s2]
  float*  gs2   = (float*)(ws + 53248);        // NREP x [128 s1 | 128 s2]
  u16*    featT = (u16*)(ws + 262144);         // 8 MiB
  u16*    xyzB  = (u16*)(ws + 8650752);        // 512 KiB (b,n -> 4x bf16)
  u16*    y0    = (u16*)(ws + 9699328);        // 64 MiB
  u16*    y1    = (u16*)(ws + 76808192);       // 64 MiB (end 143,917,056)
  u32*    gm    = (u32*)(ws + 9699328);        // y0 area; y0 dead after L1 (8 MiB packed)

  hipLaunchKernelGGL(prep_all, dim3(4433), dim3(256), 0, stream,
                     in_feat, in_xyz, W0, W1, W2, featT, xyzB, Wb, gs0);

  hipLaunchKernelGGL((gemm_layer<3, 64, true, false>), dim3(2048), dim3(256), 0, stream,
                     featT, xyzB, out_xyz, nbr, Wb, nullptr, nullptr, nullptr,
                     y0, nullptr, gs0);

  hipLaunchKernelGGL((gemm_layer<2, 64, false, false>), dim3(2048), dim3(256), 0, stream,
                     y0, nullptr, nullptr, nullptr, Wb + 6656, gs0, g0, b0,
                     y1, nullptr, gs1);

  hipLaunchKernelGGL((gemm_layer<2, 128, false, true>), dim3(2048), dim3(256), 0, stream,
                     y1, nullptr, nullptr, nullptr, Wb + 11264, gs1, g1, b1,
                     nullptr, gm, gs2);

  hipLaunchKernelGGL(final_out, dim3(1024), dim3(256), 0, stream, gm, gs2, g2, b2, out);
}